// Round 14
// baseline (2028.946 us; speedup 1.0000x reference)
//
#include <hip/hip_runtime.h>

// SentimentLSTM: B=64, T=512, E=128, H=256, V=100000, O=1
// outputs: sig_out[64], hT[1,64,256], cT[1,64,256] -> 32832 f32
//
// k_rec: 4 blocks = 2 group-pairs x 2 halves, STAGGERED dual-group.
//   Block (gpair, half): groups {2gp, 2gp+1} x 16 batches, units
//   half*128..+127, all gates. W fragments shared by both groups
//   (128 bf16x8 regs -> AGPRs). Per double-step, program order:
//   [A: par-MFMA, update, tagged store] [B: same] B1
//   [shadows: cinit+own-MFMA(t+1) for A,B + heads(t)] [A poll] [B poll] B2.
//   A's coherence latency is absorbed by B's compute + both shadows.
//
// ws layout:
//   gx3  bf16 [T][8 slot][8 w][64 lane][16]  67,108,864 B  (lane-major)
//   hx   u64  [2 par][8 slot][1024]             131,072 B
//   weff f32  [257]                               1,028 B

#define BATCH 64
#define TSTEPS 512
#define EDIM 128
#define HDIM 256
#define G4H 1024

typedef short bf16x8 __attribute__((ext_vector_type(8)));
typedef short bf16x4 __attribute__((ext_vector_type(4)));
typedef float f32x4 __attribute__((ext_vector_type(4)));

__device__ __forceinline__ unsigned short f2bf(float f) {
  unsigned u = __builtin_bit_cast(unsigned, f);
  return (unsigned short)((u + 0x7fffu + ((u >> 16) & 1u)) >> 16);
}
__device__ __forceinline__ float bf2f(unsigned short h) {
  unsigned u = ((unsigned)h) << 16;
  return __builtin_bit_cast(float, u);
}
__device__ __forceinline__ unsigned pk2(float a, float b) {
  return (unsigned)f2bf(a) | ((unsigned)f2bf(b) << 16);
}
__device__ __forceinline__ float fsig(float x) {
  return __builtin_amdgcn_rcpf(1.f + __expf(-x));
}
__device__ __forceinline__ float ftanh(float x) {
  return 1.f - 2.f * __builtin_amdgcn_rcpf(__expf(2.f * x) + 1.f);
}
__device__ __forceinline__ bf16x8 ldfrag(const unsigned short* p) {
  bf16x4 a = *(const bf16x4*)p;
  bf16x4 b = *(const bf16x4*)(p + 16);
  return __builtin_shufflevector(a, b, 0, 1, 2, 3, 4, 5, 6, 7);
}
__device__ __forceinline__ bf16x8 pack8(float4 v0, float4 v1) {
  bf16x8 f;
  f[0] = (short)f2bf(v0.x); f[1] = (short)f2bf(v0.y);
  f[2] = (short)f2bf(v0.z); f[3] = (short)f2bf(v0.w);
  f[4] = (short)f2bf(v1.x); f[5] = (short)f2bf(v1.y);
  f[6] = (short)f2bf(v1.z); f[7] = (short)f2bf(v1.w);
  return f;
}

// ---------------- K1: gx3[lane-major layout] = emb[x] @ W_ih^T + b_ih ------
__global__ __launch_bounds__(256) void k_gx(const int* __restrict__ x,
                                            const float* __restrict__ emb,
                                            const float* __restrict__ Wih,
                                            const float* __restrict__ bih,
                                            unsigned short* __restrict__ gx3) {
  const int t = blockIdx.x;
  const int g0 = blockIdx.y * 64;
  const int tid = threadIdx.x;
  __shared__ unsigned short Al[64 * 136];
  __shared__ unsigned short Bl[64 * 136];
  __shared__ int tok[64];
  if (tid < 64) tok[tid] = x[tid * TSTEPS + t];
  __syncthreads();
  {
    const int r = tid >> 2, c0 = (tid & 3) * 32;
    const float* asrc = emb + (size_t)tok[r] * EDIM + c0;
    const float* bsrc = Wih + (size_t)(g0 + r) * EDIM + c0;
#pragma unroll
    for (int s = 0; s < 32; s += 8) {
      float4 a0 = *(const float4*)(asrc + s);
      float4 a1 = *(const float4*)(asrc + s + 4);
      uint4 pa = {pk2(a0.x, a0.y), pk2(a0.z, a0.w), pk2(a1.x, a1.y), pk2(a1.z, a1.w)};
      *(uint4*)&Al[r * 136 + c0 + s] = pa;
      float4 b0 = *(const float4*)(bsrc + s);
      float4 b1 = *(const float4*)(bsrc + s + 4);
      uint4 pb = {pk2(b0.x, b0.y), pk2(b0.z, b0.w), pk2(b1.x, b1.y), pk2(b1.z, b1.w)};
      *(uint4*)&Bl[r * 136 + c0 + s] = pb;
    }
  }
  __syncthreads();
  const int lane = tid & 63, w = tid >> 6;
  const int lo = lane & 15, hi = lane >> 4;
  const int mb = (w & 1) * 32, nb = (w >> 1) * 32;
  f32x4 acc[2][2];
#pragma unroll
  for (int jj = 0; jj < 2; ++jj) {
    float bv = bih[g0 + nb + jj * 16 + lo];
    acc[0][jj] = (f32x4){bv, bv, bv, bv};
    acc[1][jj] = acc[0][jj];
  }
#pragma unroll
  for (int kk = 0; kk < 4; ++kk) {
    bf16x8 af0 = ldfrag(&Al[(mb + lo) * 136 + kk * 32 + hi * 4]);
    bf16x8 af1 = ldfrag(&Al[(mb + 16 + lo) * 136 + kk * 32 + hi * 4]);
    bf16x8 bf0 = ldfrag(&Bl[(nb + lo) * 136 + kk * 32 + hi * 4]);
    bf16x8 bf1 = ldfrag(&Bl[(nb + 16 + lo) * 136 + kk * 32 + hi * 4]);
    acc[0][0] = __builtin_amdgcn_mfma_f32_16x16x32_bf16(af0, bf0, acc[0][0], 0, 0, 0);
    acc[0][1] = __builtin_amdgcn_mfma_f32_16x16x32_bf16(af0, bf1, acc[0][1], 0, 0, 0);
    acc[1][0] = __builtin_amdgcn_mfma_f32_16x16x32_bf16(af1, bf0, acc[1][0], 0, 0, 0);
    acc[1][1] = __builtin_amdgcn_mfma_f32_16x16x32_bf16(af1, bf1, acc[1][1], 0, 0, 0);
  }
#pragma unroll
  for (int i = 0; i < 2; ++i)
#pragma unroll
    for (int jj = 0; jj < 2; ++jj) {
      int grp = (w & 1) * 2 + i;
      int col = g0 + nb + jj * 16 + lo;
      int g = col >> 8, jc = col & 255;
      int halfb = jc >> 7, wv = (jc >> 4) & 7, lov = jc & 15;
      size_t base = (((size_t)(t * 8 + grp * 2 + halfb) * 8 + wv) * 64 +
                     (hi * 16 + lov)) * 16 + g * 4;
      unsigned long long val =
          (unsigned long long)pk2(acc[i][jj][0], acc[i][jj][1]) |
          ((unsigned long long)pk2(acc[i][jj][2], acc[i][jj][3]) << 32);
      *(unsigned long long*)&gx3[base] = val;
    }
}

// ---------------- K2: recurrence, staggered dual-group ----------------------
__global__ __launch_bounds__(512, 2) void k_rec(const unsigned short* __restrict__ gx3,
                                                const float* __restrict__ Whh,
                                                const float* __restrict__ bhh,
                                                const float* __restrict__ weff,
                                                unsigned long long* __restrict__ hx,
                                                float* __restrict__ out) {
  const int tid = threadIdx.x;
  const int bp = blockIdx.x;             // 0..3
  const int gpair = bp >> 1, half = bp & 1;
  const int gA = gpair * 2, gB = gA + 1;
  const int b0A = gA * 16, b0B = gB * 16;
  const int slotA = gA * 2 + half, slotB = gB * 2 + half;
  const int lane = tid & 63, w = tid >> 6;
  const int lo = lane & 15, hi = lane >> 4;
  const int j = half * 128 + w * 16 + lo;
  __shared__ unsigned short h_lds[2][2][32 * 136];  // [grp][buf][granule][b][8]
  bf16x8 wf[4][8];
  float bhv[4];
#pragma unroll
  for (int g = 0; g < 4; ++g) {
    const float* wr = Whh + (size_t)(g * 256 + j) * HDIM;
    bhv[g] = bhh[g * 256 + j];
#pragma unroll
    for (int kk = 0; kk < 8; ++kk) {
      const float* p = wr + kk * 32 + hi * 8;
      wf[g][kk] = pack8(*(const float4*)p, *(const float4*)(p + 4));
    }
  }
  const int hb_b = tid >> 5, hb_g = tid & 31;
  float wv8[8];
#pragma unroll
  for (int e = 0; e < 8; ++e) wv8[e] = weff[hb_g * 8 + e];
  const float c0 = weff[256];
  float sigA = 0.f, sigB = 0.f;
  for (int i = tid; i < 32 * 136 / 2; i += 512) {
    ((unsigned*)h_lds[0][0])[i] = 0u;
    ((unsigned*)h_lds[1][0])[i] = 0u;
  }
  const unsigned short* gpA = gx3 + (((size_t)slotA * 8 + w) * 64 + lane) * 16;
  const unsigned short* gpB = gx3 + (((size_t)slotB * 8 + w) * 64 + lane) * 16;
  float cA[4] = {0.f, 0.f, 0.f, 0.f}, cB[4] = {0.f, 0.f, 0.f, 0.f};
  float hvA[4], hvB[4];
  f32x4 accA[4], accB[4];
  unsigned GA[8], GB[8];
  const int ob = (j >> 3) * 136 + (j & 7);
  const int jp = ((half ^ 1) * 128) + ((tid >> 6) << 4) + (tid & 15);
  const int hip = (tid >> 4) & 3;
  const int pb = (jp >> 3) * 136 + (jp & 7);

  auto gx_issue = [&](const unsigned short* gp, int st, unsigned (&G)[8]) {
    const unsigned short* q = gp + (size_t)st * 65536;
    uint4 a = *(const uint4*)(q);
    uint4 b = *(const uint4*)(q + 8);
    G[0] = a.x; G[1] = a.y; G[2] = a.z; G[3] = a.w;
    G[4] = b.x; G[5] = b.y; G[6] = b.z; G[7] = b.w;
  };
  auto cinit = [&](f32x4 (&acc)[4], const unsigned (&G)[8]) {
#pragma unroll
    for (int g = 0; g < 4; ++g)
#pragma unroll
      for (int r = 0; r < 4; ++r) {
        unsigned word = G[g * 2 + (r >> 1)];
        unsigned short v = (r & 1) ? (unsigned short)(word >> 16) : (unsigned short)word;
        acc[g][r] = bf2f(v) + bhv[g];
      }
  };
  auto mfma_own = [&](f32x4 (&acc)[4], const unsigned short* hbuf) {
    if (half == 0) {
#pragma unroll
      for (int kk = 0; kk < 4; ++kk) {
        bf16x8 a = *(const bf16x8*)&hbuf[(kk * 4 + hi) * 136 + lo * 8];
#pragma unroll
        for (int g = 0; g < 4; ++g)
          acc[g] = __builtin_amdgcn_mfma_f32_16x16x32_bf16(a, wf[g][kk], acc[g], 0, 0, 0);
      }
    } else {
#pragma unroll
      for (int kk = 4; kk < 8; ++kk) {
        bf16x8 a = *(const bf16x8*)&hbuf[(kk * 4 + hi) * 136 + lo * 8];
#pragma unroll
        for (int g = 0; g < 4; ++g)
          acc[g] = __builtin_amdgcn_mfma_f32_16x16x32_bf16(a, wf[g][kk], acc[g], 0, 0, 0);
      }
    }
  };
  auto mfma_par = [&](f32x4 (&acc)[4], const unsigned short* hbuf) {
    if (half == 0) {
#pragma unroll
      for (int kk = 4; kk < 8; ++kk) {
        bf16x8 a = *(const bf16x8*)&hbuf[(kk * 4 + hi) * 136 + lo * 8];
#pragma unroll
        for (int g = 0; g < 4; ++g)
          acc[g] = __builtin_amdgcn_mfma_f32_16x16x32_bf16(a, wf[g][kk], acc[g], 0, 0, 0);
      }
    } else {
#pragma unroll
      for (int kk = 0; kk < 4; ++kk) {
        bf16x8 a = *(const bf16x8*)&hbuf[(kk * 4 + hi) * 136 + lo * 8];
#pragma unroll
        for (int g = 0; g < 4; ++g)
          acc[g] = __builtin_amdgcn_mfma_f32_16x16x32_bf16(a, wf[g][kk], acc[g], 0, 0, 0);
      }
    }
  };
  auto upd = [&](int t, f32x4 (&acc)[4], float (&c)[4], float (&hv)[4],
                 int slot, unsigned short* ldsNxt) {
    const unsigned wt = (unsigned)(t + 1);
    unsigned short hbf[4];
#pragma unroll
    for (int r = 0; r < 4; ++r) {
      float iv = fsig(acc[0][r]), fv = fsig(acc[1][r]);
      float gv = ftanh(acc[2][r]), ov = fsig(acc[3][r]);
      c[r] = fv * c[r] + iv * gv;
      hv[r] = ov * ftanh(c[r]);
      hbf[r] = f2bf(hv[r]);
    }
    const int par = (int)(wt & 1u);
    unsigned long long* dst = &hx[((size_t)(par * 8 + slot)) * 1024 + w * 128 + lane * 2];
    const unsigned long long tg = ((unsigned long long)wt) << 32;
    __hip_atomic_store(&dst[0], tg | (unsigned long long)pk2(hv[0], hv[1]),
                       __ATOMIC_RELAXED, __HIP_MEMORY_SCOPE_AGENT);
    __hip_atomic_store(&dst[1], tg | (unsigned long long)pk2(hv[2], hv[3]),
                       __ATOMIC_RELAXED, __HIP_MEMORY_SCOPE_AGENT);
    asm volatile("" ::: "memory");  // don't sink stores past later spin loops
#pragma unroll
    for (int r = 0; r < 4; ++r) ldsNxt[ob + (hi * 4 + r) * 8] = hbf[r];
  };
  auto head = [&](const unsigned short* hbuf, float& sig) {
    bf16x8 hh = *(const bf16x8*)&hbuf[hb_g * 136 + hb_b * 8];
    float s = 0.f;
#pragma unroll
    for (int e = 0; e < 8; ++e) s += bf2f((unsigned short)hh[e]) * wv8[e];
    s += __shfl_xor(s, 1);  s += __shfl_xor(s, 2);  s += __shfl_xor(s, 4);
    s += __shfl_xor(s, 8);  s += __shfl_xor(s, 16);
    sig += fsig(s + c0);
  };
  auto pollw = [&](int t, int pslot, unsigned short* ldsNxt) {
    const unsigned wt = (unsigned)(t + 1);
    const int par = (int)(wt & 1u);
    unsigned long long* src = &hx[((size_t)(par * 8 + pslot)) * 1024 + tid * 2];
    unsigned long long a0 = __hip_atomic_load(&src[0], __ATOMIC_RELAXED, __HIP_MEMORY_SCOPE_AGENT);
    unsigned long long a1 = __hip_atomic_load(&src[1], __ATOMIC_RELAXED, __HIP_MEMORY_SCOPE_AGENT);
    unsigned long long b0 = __hip_atomic_load(&src[0], __ATOMIC_RELAXED, __HIP_MEMORY_SCOPE_AGENT);
    unsigned long long b1 = __hip_atomic_load(&src[1], __ATOMIC_RELAXED, __HIP_MEMORY_SCOPE_AGENT);
    unsigned long long v0, v1;
    for (;;) {
      if ((unsigned)(a0 >> 32) == wt && (unsigned)(a1 >> 32) == wt) { v0 = a0; v1 = a1; break; }
      a0 = b0; a1 = b1;
      b0 = __hip_atomic_load(&src[0], __ATOMIC_RELAXED, __HIP_MEMORY_SCOPE_AGENT);
      b1 = __hip_atomic_load(&src[1], __ATOMIC_RELAXED, __HIP_MEMORY_SCOPE_AGENT);
    }
    ldsNxt[pb + (hip * 4 + 0) * 8] = (unsigned short)v0;
    ldsNxt[pb + (hip * 4 + 1) * 8] = (unsigned short)(v0 >> 16);
    ldsNxt[pb + (hip * 4 + 2) * 8] = (unsigned short)v1;
    ldsNxt[pb + (hip * 4 + 3) * 8] = (unsigned short)(v1 >> 16);
  };

  // pre-loop: gx(0) -> acc (h(0)=0: buffers zeroed, own/par MFMAs add 0)
  gx_issue(gpA, 0, GA);
  gx_issue(gpB, 0, GB);
  cinit(accA, GA);
  cinit(accB, GB);
  __syncthreads();
  for (int t = 0; t < TSTEPS; ++t) {
    const int cur = t & 1, nxt = cur ^ 1;
    if (t + 1 < TSTEPS) { gx_issue(gpA, t + 1, GA); gx_issue(gpB, t + 1, GB); }
    // A: complete gates(t), update, store  (Λ_A starts here)
    mfma_par(accA, &h_lds[0][cur][0]);
    upd(t, accA, cA, hvA, slotA, &h_lds[0][nxt][0]);
    // B: same (~700 cyc, hides Λ_A)
    mfma_par(accB, &h_lds[1][cur][0]);
    upd(t, accB, cB, hvB, slotB, &h_lds[1][nxt][0]);
    __syncthreads();                           // B1: own halves visible
    // shadows (hide more of Λ): next-step C-init + own-half MFMA + heads
    if (t < TSTEPS - 1) {
      cinit(accA, GA);
      mfma_own(accA, &h_lds[0][nxt][0]);
      cinit(accB, GB);
      mfma_own(accB, &h_lds[1][nxt][0]);
    }
    if (t > 0) {
      head(&h_lds[0][cur][0], sigA);
      head(&h_lds[1][cur][0], sigB);
    }
    // polls: A first (Λ_A mostly elapsed), then B (even more elapsed)
    pollw(t, slotA ^ 1, &h_lds[0][nxt][0]);
    pollw(t, slotB ^ 1, &h_lds[1][nxt][0]);
    __syncthreads();                           // B2
  }
  // final heads: h(512) lives in buf 0 of each group
  head(&h_lds[0][0][0], sigA);
  head(&h_lds[1][0][0], sigB);
  if (half == 0 && hb_g == 0) {
    out[b0A + hb_b] = sigA * (1.f / 512.f);
    out[b0B + hb_b] = sigB * (1.f / 512.f);
  }
#pragma unroll
  for (int r = 0; r < 4; ++r) {
    const int bA = b0A + hi * 4 + r;
    const int bB = b0B + hi * 4 + r;
    out[64 + bA * HDIM + j] = hvA[r];
    out[64 + BATCH * HDIM + bA * HDIM + j] = cA[r];
    out[64 + bB * HDIM + j] = hvB[r];
    out[64 + BATCH * HDIM + bB * HDIM + j] = cB[r];
  }
}

// ---------------- K3: w_eff[k] = sum_j Wf[j]*Wm[j][k]; weff[256] = bm.Wf+bf --
__global__ __launch_bounds__(256) void k_weff(const float* __restrict__ Wm,
                                              const float* __restrict__ bm,
                                              const float* __restrict__ Wf,
                                              const float* __restrict__ bfb,
                                              float* __restrict__ weff) {
  const int k = threadIdx.x;
  __shared__ float red[256];
  float acc = 0.f;
#pragma unroll 8
  for (int jj = 0; jj < 256; ++jj) acc += Wf[jj] * Wm[jj * 256 + k];
  weff[k] = acc;
  red[k] = bm[k] * Wf[k];
  __syncthreads();
  for (int s = 128; s > 0; s >>= 1) {
    if (k < s) red[k] += red[k + s];
    __syncthreads();
  }
  if (k == 0) weff[256] = red[0] + bfb[0];
}

extern "C" void kernel_launch(void* const* d_in, const int* in_sizes, int n_in,
                              void* d_out, int out_size, void* d_ws, size_t ws_size,
                              hipStream_t stream) {
  (void)in_sizes; (void)n_in; (void)out_size; (void)ws_size;
  const int* x = (const int*)d_in[0];
  const float* emb = (const float*)d_in[1];
  const float* Wih = (const float*)d_in[2];
  const float* Whh = (const float*)d_in[3];
  const float* bih = (const float*)d_in[4];
  const float* bhh = (const float*)d_in[5];
  const float* Wm  = (const float*)d_in[6];
  const float* bm  = (const float*)d_in[7];
  const float* Wf  = (const float*)d_in[8];
  const float* bf  = (const float*)d_in[9];
  float* out = (float*)d_out;
  char* ws = (char*)d_ws;
  const size_t gx_bytes = (size_t)TSTEPS * BATCH * G4H * 2;  // 67,108,864
  const size_t hx_bytes = (size_t)2 * 8 * 1024 * 8;          // 131,072
  unsigned short* gx3 = (unsigned short*)ws;
  unsigned long long* hx = (unsigned long long*)(ws + gx_bytes);
  float* weff = (float*)(ws + gx_bytes + hx_bytes);
  hipMemsetAsync(hx, 0, hx_bytes, stream);  // tags start at 0 every launch
  k_gx<<<dim3(512, 16), 256, 0, stream>>>(x, emb, Wih, bih, gx3);
  k_weff<<<1, 256, 0, stream>>>(Wm, bm, Wf, bf, weff);
  k_rec<<<4, 512, 0, stream>>>(gx3, Whh, bhh, weff, hx, out);
}

// Round 15
// 1190.631 us; speedup vs baseline: 1.7041x; 1.7041x over previous
//
#include <hip/hip_runtime.h>

// SentimentLSTM: B=64, T=512, E=128, H=256, V=100000, O=1
// outputs: sig_out[64], hT[1,64,256], cT[1,64,256] -> 32832 f32
//
// k_rec (R10 champion + barrier-drain fix): 8 blocks = 4 groups x 2 halves.
//   KEY FIX: __syncthreads() emits s_waitcnt vmcnt(0) before s_barrier, which
//   drained the exchange-store ack (~1600 cyc) BEFORE the shadow ran (the m97
//   barrier-drain pathology). Replaced with lgkm-only barriers
//   (s_waitcnt lgkmcnt(0); s_barrier) so the tagged stores stay in flight
//   across the barrier and the shadow (cinit + own-half MFMA + head) overlaps
//   the coherence latency. Poll sample loads issued EARLY (right after the
//   stores, T14) and checked after the shadow.
//
// ws layout:
//   gx3  bf16 [T][8 slot][8 w][64 lane][16]  67,108,864 B  (lane-major)
//   hx   u64  [2 par][8 slot][1024]             131,072 B
//   weff f32  [257]                               1,028 B

#define BATCH 64
#define TSTEPS 512
#define EDIM 128
#define HDIM 256
#define G4H 1024

typedef short bf16x8 __attribute__((ext_vector_type(8)));
typedef short bf16x4 __attribute__((ext_vector_type(4)));
typedef float f32x4 __attribute__((ext_vector_type(4)));

// lgkm-only barrier: orders LDS, leaves global stores in flight (m139)
#define LGKM_BARRIER() asm volatile("s_waitcnt lgkmcnt(0)\ns_barrier" ::: "memory")

__device__ __forceinline__ unsigned short f2bf(float f) {
  unsigned u = __builtin_bit_cast(unsigned, f);
  return (unsigned short)((u + 0x7fffu + ((u >> 16) & 1u)) >> 16);
}
__device__ __forceinline__ float bf2f(unsigned short h) {
  unsigned u = ((unsigned)h) << 16;
  return __builtin_bit_cast(float, u);
}
__device__ __forceinline__ unsigned pk2(float a, float b) {
  return (unsigned)f2bf(a) | ((unsigned)f2bf(b) << 16);
}
__device__ __forceinline__ float fsig(float x) {
  return __builtin_amdgcn_rcpf(1.f + __expf(-x));
}
__device__ __forceinline__ float ftanh(float x) {
  return 1.f - 2.f * __builtin_amdgcn_rcpf(__expf(2.f * x) + 1.f);
}
__device__ __forceinline__ bf16x8 ldfrag(const unsigned short* p) {
  bf16x4 a = *(const bf16x4*)p;
  bf16x4 b = *(const bf16x4*)(p + 16);
  return __builtin_shufflevector(a, b, 0, 1, 2, 3, 4, 5, 6, 7);
}
__device__ __forceinline__ bf16x8 pack8(float4 v0, float4 v1) {
  bf16x8 f;
  f[0] = (short)f2bf(v0.x); f[1] = (short)f2bf(v0.y);
  f[2] = (short)f2bf(v0.z); f[3] = (short)f2bf(v0.w);
  f[4] = (short)f2bf(v1.x); f[5] = (short)f2bf(v1.y);
  f[6] = (short)f2bf(v1.z); f[7] = (short)f2bf(v1.w);
  return f;
}

// ---------------- K1: gx3[lane-major layout] = emb[x] @ W_ih^T + b_ih ------
__global__ __launch_bounds__(256) void k_gx(const int* __restrict__ x,
                                            const float* __restrict__ emb,
                                            const float* __restrict__ Wih,
                                            const float* __restrict__ bih,
                                            unsigned short* __restrict__ gx3) {
  const int t = blockIdx.x;
  const int g0 = blockIdx.y * 64;
  const int tid = threadIdx.x;
  __shared__ unsigned short Al[64 * 136];
  __shared__ unsigned short Bl[64 * 136];
  __shared__ int tok[64];
  if (tid < 64) tok[tid] = x[tid * TSTEPS + t];
  __syncthreads();
  {
    const int r = tid >> 2, c0 = (tid & 3) * 32;
    const float* asrc = emb + (size_t)tok[r] * EDIM + c0;
    const float* bsrc = Wih + (size_t)(g0 + r) * EDIM + c0;
#pragma unroll
    for (int s = 0; s < 32; s += 8) {
      float4 a0 = *(const float4*)(asrc + s);
      float4 a1 = *(const float4*)(asrc + s + 4);
      uint4 pa = {pk2(a0.x, a0.y), pk2(a0.z, a0.w), pk2(a1.x, a1.y), pk2(a1.z, a1.w)};
      *(uint4*)&Al[r * 136 + c0 + s] = pa;
      float4 b0 = *(const float4*)(bsrc + s);
      float4 b1 = *(const float4*)(bsrc + s + 4);
      uint4 pb = {pk2(b0.x, b0.y), pk2(b0.z, b0.w), pk2(b1.x, b1.y), pk2(b1.z, b1.w)};
      *(uint4*)&Bl[r * 136 + c0 + s] = pb;
    }
  }
  __syncthreads();
  const int lane = tid & 63, w = tid >> 6;
  const int lo = lane & 15, hi = lane >> 4;
  const int mb = (w & 1) * 32, nb = (w >> 1) * 32;
  f32x4 acc[2][2];
#pragma unroll
  for (int jj = 0; jj < 2; ++jj) {
    float bv = bih[g0 + nb + jj * 16 + lo];
    acc[0][jj] = (f32x4){bv, bv, bv, bv};
    acc[1][jj] = acc[0][jj];
  }
#pragma unroll
  for (int kk = 0; kk < 4; ++kk) {
    bf16x8 af0 = ldfrag(&Al[(mb + lo) * 136 + kk * 32 + hi * 4]);
    bf16x8 af1 = ldfrag(&Al[(mb + 16 + lo) * 136 + kk * 32 + hi * 4]);
    bf16x8 bf0 = ldfrag(&Bl[(nb + lo) * 136 + kk * 32 + hi * 4]);
    bf16x8 bf1 = ldfrag(&Bl[(nb + 16 + lo) * 136 + kk * 32 + hi * 4]);
    acc[0][0] = __builtin_amdgcn_mfma_f32_16x16x32_bf16(af0, bf0, acc[0][0], 0, 0, 0);
    acc[0][1] = __builtin_amdgcn_mfma_f32_16x16x32_bf16(af0, bf1, acc[0][1], 0, 0, 0);
    acc[1][0] = __builtin_amdgcn_mfma_f32_16x16x32_bf16(af1, bf0, acc[1][0], 0, 0, 0);
    acc[1][1] = __builtin_amdgcn_mfma_f32_16x16x32_bf16(af1, bf1, acc[1][1], 0, 0, 0);
  }
#pragma unroll
  for (int i = 0; i < 2; ++i)
#pragma unroll
    for (int jj = 0; jj < 2; ++jj) {
      int grp = (w & 1) * 2 + i;
      int col = g0 + nb + jj * 16 + lo;
      int g = col >> 8, jc = col & 255;
      int halfb = jc >> 7, wv = (jc >> 4) & 7, lov = jc & 15;
      size_t base = (((size_t)(t * 8 + grp * 2 + halfb) * 8 + wv) * 64 +
                     (hi * 16 + lov)) * 16 + g * 4;
      unsigned long long val =
          (unsigned long long)pk2(acc[i][jj][0], acc[i][jj][1]) |
          ((unsigned long long)pk2(acc[i][jj][2], acc[i][jj][3]) << 32);
      *(unsigned long long*)&gx3[base] = val;
    }
}

// ---------------- K2: recurrence, split-K + lgkm-only barriers --------------
__global__ __launch_bounds__(512, 2) void k_rec(const unsigned short* __restrict__ gx3,
                                                const float* __restrict__ Whh,
                                                const float* __restrict__ bhh,
                                                const float* __restrict__ weff,
                                                unsigned long long* __restrict__ hx,
                                                float* __restrict__ out) {
  const int tid = threadIdx.x;
  const int bp = blockIdx.x;             // 0..7
  const int grp = bp >> 1, half = bp & 1;
  const int b0 = grp * 16;
  const int lane = tid & 63, w = tid >> 6;
  const int lo = lane & 15, hi = lane >> 4;
  const int j = half * 128 + w * 16 + lo;
  __shared__ unsigned short h_lds[2][32 * 136];  // k-major [granule][batch][8]
  bf16x8 wf[4][8];
  float bhv[4];
#pragma unroll
  for (int g = 0; g < 4; ++g) {
    const float* wr = Whh + (size_t)(g * 256 + j) * HDIM;
    bhv[g] = bhh[g * 256 + j];
#pragma unroll
    for (int kk = 0; kk < 8; ++kk) {
      const float* p = wr + kk * 32 + hi * 8;
      wf[g][kk] = pack8(*(const float4*)p, *(const float4*)(p + 4));
    }
  }
  const int hb_b = tid >> 5, hb_g = tid & 31;
  float wv8[8];
#pragma unroll
  for (int e = 0; e < 8; ++e) wv8[e] = weff[hb_g * 8 + e];
  const float c0 = weff[256];
  float sig_acc = 0.f;
  for (int i = tid; i < 32 * 136 / 2; i += 512) ((unsigned*)h_lds[0])[i] = 0u;
  const unsigned short* gp = gx3 + (((size_t)bp * 8 + w) * 64 + lane) * 16;
  unsigned gwE[8], gwO[8];
  {
    uint4 a = *(const uint4*)(gp);
    uint4 b = *(const uint4*)(gp + 8);
    gwE[0] = a.x; gwE[1] = a.y; gwE[2] = a.z; gwE[3] = a.w;
    gwE[4] = b.x; gwE[5] = b.y; gwE[6] = b.z; gwE[7] = b.w;
    uint4 c2 = *(const uint4*)(gp + 65536);
    uint4 d2 = *(const uint4*)(gp + 65536 + 8);
    gwO[0] = c2.x; gwO[1] = c2.y; gwO[2] = c2.z; gwO[3] = c2.w;
    gwO[4] = d2.x; gwO[5] = d2.y; gwO[6] = d2.z; gwO[7] = d2.w;
  }
  float c[4] = {0.f, 0.f, 0.f, 0.f};
  float hv[4];
  f32x4 acc[4];
  const int ob = (j >> 3) * 136 + (j & 7);
  const int jp = ((half ^ 1) * 128) + ((tid >> 6) << 4) + (tid & 15);
  const int hip = (tid >> 4) & 3;
  const int pb = (jp >> 3) * 136 + (jp & 7);
  __syncthreads();

  auto cinit = [&](const unsigned (&G)[8]) {
#pragma unroll
    for (int g = 0; g < 4; ++g)
#pragma unroll
      for (int r = 0; r < 4; ++r) {
        unsigned word = G[g * 2 + (r >> 1)];
        unsigned short v = (r & 1) ? (unsigned short)(word >> 16) : (unsigned short)word;
        acc[g][r] = bf2f(v) + bhv[g];
      }
  };
  auto mfma_own = [&](int buf) {  // own-half K: static kk ranges per half
    if (half == 0) {
#pragma unroll
      for (int kk = 0; kk < 4; ++kk) {
        bf16x8 a = *(const bf16x8*)&h_lds[buf][(kk * 4 + hi) * 136 + lo * 8];
#pragma unroll
        for (int g = 0; g < 4; ++g)
          acc[g] = __builtin_amdgcn_mfma_f32_16x16x32_bf16(a, wf[g][kk], acc[g], 0, 0, 0);
      }
    } else {
#pragma unroll
      for (int kk = 4; kk < 8; ++kk) {
        bf16x8 a = *(const bf16x8*)&h_lds[buf][(kk * 4 + hi) * 136 + lo * 8];
#pragma unroll
        for (int g = 0; g < 4; ++g)
          acc[g] = __builtin_amdgcn_mfma_f32_16x16x32_bf16(a, wf[g][kk], acc[g], 0, 0, 0);
      }
    }
  };
  auto mfma_par = [&](int buf) {  // partner-half K
    if (half == 0) {
#pragma unroll
      for (int kk = 4; kk < 8; ++kk) {
        bf16x8 a = *(const bf16x8*)&h_lds[buf][(kk * 4 + hi) * 136 + lo * 8];
#pragma unroll
        for (int g = 0; g < 4; ++g)
          acc[g] = __builtin_amdgcn_mfma_f32_16x16x32_bf16(a, wf[g][kk], acc[g], 0, 0, 0);
      }
    } else {
#pragma unroll
      for (int kk = 0; kk < 4; ++kk) {
        bf16x8 a = *(const bf16x8*)&h_lds[buf][(kk * 4 + hi) * 136 + lo * 8];
#pragma unroll
        for (int g = 0; g < 4; ++g)
          acc[g] = __builtin_amdgcn_mfma_f32_16x16x32_bf16(a, wf[g][kk], acc[g], 0, 0, 0);
      }
    }
  };
  auto update_store = [&](int t) {  // U(t) + S(t) + own W(t)
    const unsigned wt = (unsigned)(t + 1);
    unsigned short hbf[4];
#pragma unroll
    for (int r = 0; r < 4; ++r) {
      float iv = fsig(acc[0][r]), fv = fsig(acc[1][r]);
      float gv = ftanh(acc[2][r]), ov = fsig(acc[3][r]);
      c[r] = fv * c[r] + iv * gv;
      hv[r] = ov * ftanh(c[r]);
      hbf[r] = f2bf(hv[r]);
    }
    const int par = (int)(wt & 1u);
    unsigned long long* dst = &hx[((size_t)(par * 8 + bp)) * 1024 + w * 128 + lane * 2];
    const unsigned long long tg = ((unsigned long long)wt) << 32;
    __hip_atomic_store(&dst[0], tg | (unsigned long long)pk2(hv[0], hv[1]),
                       __ATOMIC_RELAXED, __HIP_MEMORY_SCOPE_AGENT);
    __hip_atomic_store(&dst[1], tg | (unsigned long long)pk2(hv[2], hv[3]),
                       __ATOMIC_RELAXED, __HIP_MEMORY_SCOPE_AGENT);
    asm volatile("" ::: "memory");
#pragma unroll
    for (int r = 0; r < 4; ++r) h_lds[par][ob + (hi * 4 + r) * 8] = hbf[r];
  };
  auto head = [&](int buf) {
    bf16x8 hh = *(const bf16x8*)&h_lds[buf][hb_g * 136 + hb_b * 8];
    float s = 0.f;
#pragma unroll
    for (int e = 0; e < 8; ++e) s += bf2f((unsigned short)hh[e]) * wv8[e];
    s += __shfl_xor(s, 1);  s += __shfl_xor(s, 2);  s += __shfl_xor(s, 4);
    s += __shfl_xor(s, 8);  s += __shfl_xor(s, 16);
    sig_acc += fsig(s + c0);
  };
  auto gx_issue = [&](int s, unsigned (&G)[8]) {
    const unsigned short* q = gp + (size_t)s * 65536;
    uint4 a = *(const uint4*)(q);
    uint4 b = *(const uint4*)(q + 8);
    G[0] = a.x; G[1] = a.y; G[2] = a.z; G[3] = a.w;
    G[4] = b.x; G[5] = b.y; G[6] = b.z; G[7] = b.w;
  };
  auto body = [&](int t, unsigned (&Gc)[8], unsigned (&Gf)[8]) {
    // entry: acc = gx(t)+bhh+own(h(t)); LDS[t&1] holds full h(t)
    if (t + 2 < TSTEPS) gx_issue(t + 2, Gf);
    mfma_par(t & 1);                 // complete gates(t)
    update_store(t);                 // h(t+1): tagged stores + own LDS write
    // early poll issue (T14): sample rides the wire during the shadow
    const unsigned wt = (unsigned)(t + 1);
    const int par = (int)(wt & 1u);
    unsigned long long* src = &hx[((size_t)(par * 8 + (bp ^ 1))) * 1024 + tid * 2];
    unsigned long long s0 = __hip_atomic_load(&src[0], __ATOMIC_RELAXED, __HIP_MEMORY_SCOPE_AGENT);
    unsigned long long s1 = __hip_atomic_load(&src[1], __ATOMIC_RELAXED, __HIP_MEMORY_SCOPE_AGENT);
    asm volatile("" ::: "memory");
    LGKM_BARRIER();                  // B1: LDS-ordered; stores stay in flight
    if (t < TSTEPS - 1) {
      cinit(Gc);                     // gx(t+1)
      mfma_own((t + 1) & 1);         // own-half of step t+1 (true shadow now)
    }
    head(t & 1);                     // head of h(t) (shadow)
    // check first sample; resample until tagged
    while ((unsigned)(s0 >> 32) != wt || (unsigned)(s1 >> 32) != wt) {
      s0 = __hip_atomic_load(&src[0], __ATOMIC_RELAXED, __HIP_MEMORY_SCOPE_AGENT);
      s1 = __hip_atomic_load(&src[1], __ATOMIC_RELAXED, __HIP_MEMORY_SCOPE_AGENT);
    }
    h_lds[par][pb + (hip * 4 + 0) * 8] = (unsigned short)s0;
    h_lds[par][pb + (hip * 4 + 1) * 8] = (unsigned short)(s0 >> 16);
    h_lds[par][pb + (hip * 4 + 2) * 8] = (unsigned short)s1;
    h_lds[par][pb + (hip * 4 + 3) * 8] = (unsigned short)(s1 >> 16);
    LGKM_BARRIER();                  // B2
  };

  // prologue: t=0 (h(0)=0 -> gates = gx(0)+bhh, no MFMA)
  cinit(gwE);
  update_store(0);
  {
    const unsigned wt = 1u;
    unsigned long long* src = &hx[((size_t)(1 * 8 + (bp ^ 1))) * 1024 + tid * 2];
    unsigned long long s0 = __hip_atomic_load(&src[0], __ATOMIC_RELAXED, __HIP_MEMORY_SCOPE_AGENT);
    unsigned long long s1 = __hip_atomic_load(&src[1], __ATOMIC_RELAXED, __HIP_MEMORY_SCOPE_AGENT);
    asm volatile("" ::: "memory");
    gx_issue(2, gwE);
    LGKM_BARRIER();                  // B1
    cinit(gwO);
    mfma_own(1);
    while ((unsigned)(s0 >> 32) != wt || (unsigned)(s1 >> 32) != wt) {
      s0 = __hip_atomic_load(&src[0], __ATOMIC_RELAXED, __HIP_MEMORY_SCOPE_AGENT);
      s1 = __hip_atomic_load(&src[1], __ATOMIC_RELAXED, __HIP_MEMORY_SCOPE_AGENT);
    }
    h_lds[1][pb + (hip * 4 + 0) * 8] = (unsigned short)s0;
    h_lds[1][pb + (hip * 4 + 1) * 8] = (unsigned short)(s0 >> 16);
    h_lds[1][pb + (hip * 4 + 2) * 8] = (unsigned short)s1;
    h_lds[1][pb + (hip * 4 + 3) * 8] = (unsigned short)(s1 >> 16);
    LGKM_BARRIER();                  // B2
  }
  // main: t = 1..510 paired, then t = 511
  for (int t = 1; t + 1 < TSTEPS - 1; t += 2) {
    body(t, gwE, gwO);
    body(t + 1, gwO, gwE);
  }
  body(TSTEPS - 1, gwE, gwO);
  head(0);                           // head of h(512) (buf 0)
  if (half == 0 && hb_g == 0) out[b0 + hb_b] = sig_acc * (1.f / 512.f);
#pragma unroll
  for (int r = 0; r < 4; ++r) {
    const int b = b0 + hi * 4 + r;
    out[64 + b * HDIM + j] = hv[r];
    out[64 + BATCH * HDIM + b * HDIM + j] = c[r];
  }
}

// ---------------- K3: w_eff[k] = sum_j Wf[j]*Wm[j][k]; weff[256] = bm.Wf+bf --
__global__ __launch_bounds__(256) void k_weff(const float* __restrict__ Wm,
                                              const float* __restrict__ bm,
                                              const float* __restrict__ Wf,
                                              const float* __restrict__ bfb,
                                              float* __restrict__ weff) {
  const int k = threadIdx.x;
  __shared__ float red[256];
  float acc = 0.f;
#pragma unroll 8
  for (int jj = 0; jj < 256; ++jj) acc += Wf[jj] * Wm[jj * 256 + k];
  weff[k] = acc;
  red[k] = bm[k] * Wf[k];
  __syncthreads();
  for (int s = 128; s > 0; s >>= 1) {
    if (k < s) red[k] += red[k + s];
    __syncthreads();
  }
  if (k == 0) weff[256] = red[0] + bfb[0];
}

extern "C" void kernel_launch(void* const* d_in, const int* in_sizes, int n_in,
                              void* d_out, int out_size, void* d_ws, size_t ws_size,
                              hipStream_t stream) {
  (void)in_sizes; (void)n_in; (void)out_size; (void)ws_size;
  const int* x = (const int*)d_in[0];
  const float* emb = (const float*)d_in[1];
  const float* Wih = (const float*)d_in[2];
  const float* Whh = (const float*)d_in[3];
  const float* bih = (const float*)d_in[4];
  const float* bhh = (const float*)d_in[5];
  const float* Wm  = (const float*)d_in[6];
  const float* bm  = (const float*)d_in[7];
  const float* Wf  = (const float*)d_in[8];
  const float* bf  = (const float*)d_in[9];
  float* out = (float*)d_out;
  char* ws = (char*)d_ws;
  const size_t gx_bytes = (size_t)TSTEPS * BATCH * G4H * 2;  // 67,108,864
  const size_t hx_bytes = (size_t)2 * 8 * 1024 * 8;          // 131,072
  unsigned short* gx3 = (unsigned short*)ws;
  unsigned long long* hx = (unsigned long long*)(ws + gx_bytes);
  float* weff = (float*)(ws + gx_bytes + hx_bytes);
  hipMemsetAsync(hx, 0, hx_bytes, stream);  // tags start at 0 every launch
  k_gx<<<dim3(512, 16), 256, 0, stream>>>(x, emb, Wih, bih, gx3);
  k_weff<<<1, 256, 0, stream>>>(Wm, bm, Wf, bf, weff);
  k_rec<<<8, 512, 0, stream>>>(gx3, Whh, bhh, weff, hx, out);
}

// Round 16
// 1034.855 us; speedup vs baseline: 1.9606x; 1.1505x over previous
//
#include <hip/hip_runtime.h>

// SentimentLSTM: B=64, T=512, E=128, H=256, V=100000, O=1
// outputs: sig_out[64], hT[1,64,256], cT[1,64,256] -> 32832 f32
//
// FINAL (R10 champion): k_rec = 8 blocks = 4 groups x 2 halves, split-K
// pipeline. Per step: partner-half MFMA -> update -> tagged store -> own LDS
// write -> B1 -> [SHADOW: C-init(t+1) + own-half MFMA(t+1) + head(t)] ->
// 2-deep pipelined poll -> partner LDS write -> B2.
// 15 rounds of variants established this as the cross-CU-latency floor
// (~4350 cyc/step = ~1200 compute + ~3100 exposed coherence RT; 512 serial
// chip-wide exchanges x ~1.8 us ~= 930 us k_rec).
//
// ws layout:
//   gx3  bf16 [T][8 slot][8 w][64 lane][16]  67,108,864 B  (lane-major)
//   hx   u64  [2 par][8 slot][1024]             131,072 B
//   weff f32  [257]                               1,028 B

#define BATCH 64
#define TSTEPS 512
#define EDIM 128
#define HDIM 256
#define G4H 1024

typedef short bf16x8 __attribute__((ext_vector_type(8)));
typedef short bf16x4 __attribute__((ext_vector_type(4)));
typedef float f32x4 __attribute__((ext_vector_type(4)));

__device__ __forceinline__ unsigned short f2bf(float f) {
  unsigned u = __builtin_bit_cast(unsigned, f);
  return (unsigned short)((u + 0x7fffu + ((u >> 16) & 1u)) >> 16);
}
__device__ __forceinline__ float bf2f(unsigned short h) {
  unsigned u = ((unsigned)h) << 16;
  return __builtin_bit_cast(float, u);
}
__device__ __forceinline__ unsigned pk2(float a, float b) {
  return (unsigned)f2bf(a) | ((unsigned)f2bf(b) << 16);
}
__device__ __forceinline__ float fsig(float x) {
  return __builtin_amdgcn_rcpf(1.f + __expf(-x));
}
__device__ __forceinline__ float ftanh(float x) {
  return 1.f - 2.f * __builtin_amdgcn_rcpf(__expf(2.f * x) + 1.f);
}
__device__ __forceinline__ bf16x8 ldfrag(const unsigned short* p) {
  bf16x4 a = *(const bf16x4*)p;
  bf16x4 b = *(const bf16x4*)(p + 16);
  return __builtin_shufflevector(a, b, 0, 1, 2, 3, 4, 5, 6, 7);
}
__device__ __forceinline__ bf16x8 pack8(float4 v0, float4 v1) {
  bf16x8 f;
  f[0] = (short)f2bf(v0.x); f[1] = (short)f2bf(v0.y);
  f[2] = (short)f2bf(v0.z); f[3] = (short)f2bf(v0.w);
  f[4] = (short)f2bf(v1.x); f[5] = (short)f2bf(v1.y);
  f[6] = (short)f2bf(v1.z); f[7] = (short)f2bf(v1.w);
  return f;
}

// ---------------- K1: gx3[lane-major layout] = emb[x] @ W_ih^T + b_ih ------
__global__ __launch_bounds__(256) void k_gx(const int* __restrict__ x,
                                            const float* __restrict__ emb,
                                            const float* __restrict__ Wih,
                                            const float* __restrict__ bih,
                                            unsigned short* __restrict__ gx3) {
  const int t = blockIdx.x;
  const int g0 = blockIdx.y * 64;
  const int tid = threadIdx.x;
  __shared__ unsigned short Al[64 * 136];
  __shared__ unsigned short Bl[64 * 136];
  __shared__ int tok[64];
  if (tid < 64) tok[tid] = x[tid * TSTEPS + t];
  __syncthreads();
  {
    const int r = tid >> 2, c0 = (tid & 3) * 32;
    const float* asrc = emb + (size_t)tok[r] * EDIM + c0;
    const float* bsrc = Wih + (size_t)(g0 + r) * EDIM + c0;
#pragma unroll
    for (int s = 0; s < 32; s += 8) {
      float4 a0 = *(const float4*)(asrc + s);
      float4 a1 = *(const float4*)(asrc + s + 4);
      uint4 pa = {pk2(a0.x, a0.y), pk2(a0.z, a0.w), pk2(a1.x, a1.y), pk2(a1.z, a1.w)};
      *(uint4*)&Al[r * 136 + c0 + s] = pa;
      float4 b0 = *(const float4*)(bsrc + s);
      float4 b1 = *(const float4*)(bsrc + s + 4);
      uint4 pb = {pk2(b0.x, b0.y), pk2(b0.z, b0.w), pk2(b1.x, b1.y), pk2(b1.z, b1.w)};
      *(uint4*)&Bl[r * 136 + c0 + s] = pb;
    }
  }
  __syncthreads();
  const int lane = tid & 63, w = tid >> 6;
  const int lo = lane & 15, hi = lane >> 4;
  const int mb = (w & 1) * 32, nb = (w >> 1) * 32;
  f32x4 acc[2][2];
#pragma unroll
  for (int jj = 0; jj < 2; ++jj) {
    float bv = bih[g0 + nb + jj * 16 + lo];
    acc[0][jj] = (f32x4){bv, bv, bv, bv};
    acc[1][jj] = acc[0][jj];
  }
#pragma unroll
  for (int kk = 0; kk < 4; ++kk) {
    bf16x8 af0 = ldfrag(&Al[(mb + lo) * 136 + kk * 32 + hi * 4]);
    bf16x8 af1 = ldfrag(&Al[(mb + 16 + lo) * 136 + kk * 32 + hi * 4]);
    bf16x8 bf0 = ldfrag(&Bl[(nb + lo) * 136 + kk * 32 + hi * 4]);
    bf16x8 bf1 = ldfrag(&Bl[(nb + 16 + lo) * 136 + kk * 32 + hi * 4]);
    acc[0][0] = __builtin_amdgcn_mfma_f32_16x16x32_bf16(af0, bf0, acc[0][0], 0, 0, 0);
    acc[0][1] = __builtin_amdgcn_mfma_f32_16x16x32_bf16(af0, bf1, acc[0][1], 0, 0, 0);
    acc[1][0] = __builtin_amdgcn_mfma_f32_16x16x32_bf16(af1, bf0, acc[1][0], 0, 0, 0);
    acc[1][1] = __builtin_amdgcn_mfma_f32_16x16x32_bf16(af1, bf1, acc[1][1], 0, 0, 0);
  }
#pragma unroll
  for (int i = 0; i < 2; ++i)
#pragma unroll
    for (int jj = 0; jj < 2; ++jj) {
      int grp = (w & 1) * 2 + i;
      int col = g0 + nb + jj * 16 + lo;
      int g = col >> 8, jc = col & 255;
      int halfb = jc >> 7, wv = (jc >> 4) & 7, lov = jc & 15;
      size_t base = (((size_t)(t * 8 + grp * 2 + halfb) * 8 + wv) * 64 +
                     (hi * 16 + lov)) * 16 + g * 4;
      unsigned long long val =
          (unsigned long long)pk2(acc[i][jj][0], acc[i][jj][1]) |
          ((unsigned long long)pk2(acc[i][jj][2], acc[i][jj][3]) << 32);
      *(unsigned long long*)&gx3[base] = val;
    }
}

// ---------------- K2: recurrence, split-K pipelined -------------------------
__global__ __launch_bounds__(512, 2) void k_rec(const unsigned short* __restrict__ gx3,
                                                const float* __restrict__ Whh,
                                                const float* __restrict__ bhh,
                                                const float* __restrict__ weff,
                                                unsigned long long* __restrict__ hx,
                                                float* __restrict__ out) {
  const int tid = threadIdx.x;
  const int bp = blockIdx.x;             // 0..7
  const int grp = bp >> 1, half = bp & 1;
  const int b0 = grp * 16;
  const int lane = tid & 63, w = tid >> 6;
  const int lo = lane & 15, hi = lane >> 4;
  const int j = half * 128 + w * 16 + lo;
  __shared__ unsigned short h_lds[2][32 * 136];  // k-major [granule][batch][8]
  bf16x8 wf[4][8];
  float bhv[4];
#pragma unroll
  for (int g = 0; g < 4; ++g) {
    const float* wr = Whh + (size_t)(g * 256 + j) * HDIM;
    bhv[g] = bhh[g * 256 + j];
#pragma unroll
    for (int kk = 0; kk < 8; ++kk) {
      const float* p = wr + kk * 32 + hi * 8;
      wf[g][kk] = pack8(*(const float4*)p, *(const float4*)(p + 4));
    }
  }
  const int hb_b = tid >> 5, hb_g = tid & 31;
  float wv8[8];
#pragma unroll
  for (int e = 0; e < 8; ++e) wv8[e] = weff[hb_g * 8 + e];
  const float c0 = weff[256];
  float sig_acc = 0.f;
  for (int i = tid; i < 32 * 136 / 2; i += 512) ((unsigned*)h_lds[0])[i] = 0u;
  const unsigned short* gp = gx3 + (((size_t)bp * 8 + w) * 64 + lane) * 16;
  unsigned gwE[8], gwO[8];
  {
    uint4 a = *(const uint4*)(gp);
    uint4 b = *(const uint4*)(gp + 8);
    gwE[0] = a.x; gwE[1] = a.y; gwE[2] = a.z; gwE[3] = a.w;
    gwE[4] = b.x; gwE[5] = b.y; gwE[6] = b.z; gwE[7] = b.w;
    uint4 c2 = *(const uint4*)(gp + 65536);
    uint4 d2 = *(const uint4*)(gp + 65536 + 8);
    gwO[0] = c2.x; gwO[1] = c2.y; gwO[2] = c2.z; gwO[3] = c2.w;
    gwO[4] = d2.x; gwO[5] = d2.y; gwO[6] = d2.z; gwO[7] = d2.w;
  }
  float c[4] = {0.f, 0.f, 0.f, 0.f};
  float hv[4];
  f32x4 acc[4];
  const int ob = (j >> 3) * 136 + (j & 7);
  const int jp = ((half ^ 1) * 128) + ((tid >> 6) << 4) + (tid & 15);
  const int hip = (tid >> 4) & 3;
  const int pb = (jp >> 3) * 136 + (jp & 7);
  __syncthreads();

  auto cinit = [&](const unsigned (&G)[8]) {
#pragma unroll
    for (int g = 0; g < 4; ++g)
#pragma unroll
      for (int r = 0; r < 4; ++r) {
        unsigned word = G[g * 2 + (r >> 1)];
        unsigned short v = (r & 1) ? (unsigned short)(word >> 16) : (unsigned short)word;
        acc[g][r] = bf2f(v) + bhv[g];
      }
  };
  auto mfma_own = [&](int buf) {  // own-half K: static kk ranges per half
    if (half == 0) {
#pragma unroll
      for (int kk = 0; kk < 4; ++kk) {
        bf16x8 a = *(const bf16x8*)&h_lds[buf][(kk * 4 + hi) * 136 + lo * 8];
#pragma unroll
        for (int g = 0; g < 4; ++g)
          acc[g] = __builtin_amdgcn_mfma_f32_16x16x32_bf16(a, wf[g][kk], acc[g], 0, 0, 0);
      }
    } else {
#pragma unroll
      for (int kk = 4; kk < 8; ++kk) {
        bf16x8 a = *(const bf16x8*)&h_lds[buf][(kk * 4 + hi) * 136 + lo * 8];
#pragma unroll
        for (int g = 0; g < 4; ++g)
          acc[g] = __builtin_amdgcn_mfma_f32_16x16x32_bf16(a, wf[g][kk], acc[g], 0, 0, 0);
      }
    }
  };
  auto mfma_par = [&](int buf) {  // partner-half K
    if (half == 0) {
#pragma unroll
      for (int kk = 4; kk < 8; ++kk) {
        bf16x8 a = *(const bf16x8*)&h_lds[buf][(kk * 4 + hi) * 136 + lo * 8];
#pragma unroll
        for (int g = 0; g < 4; ++g)
          acc[g] = __builtin_amdgcn_mfma_f32_16x16x32_bf16(a, wf[g][kk], acc[g], 0, 0, 0);
      }
    } else {
#pragma unroll
      for (int kk = 0; kk < 4; ++kk) {
        bf16x8 a = *(const bf16x8*)&h_lds[buf][(kk * 4 + hi) * 136 + lo * 8];
#pragma unroll
        for (int g = 0; g < 4; ++g)
          acc[g] = __builtin_amdgcn_mfma_f32_16x16x32_bf16(a, wf[g][kk], acc[g], 0, 0, 0);
      }
    }
  };
  auto update_store = [&](int t) {  // U(t) + S(t) + own W(t)
    const unsigned wt = (unsigned)(t + 1);
    unsigned short hbf[4];
#pragma unroll
    for (int r = 0; r < 4; ++r) {
      float iv = fsig(acc[0][r]), fv = fsig(acc[1][r]);
      float gv = ftanh(acc[2][r]), ov = fsig(acc[3][r]);
      c[r] = fv * c[r] + iv * gv;
      hv[r] = ov * ftanh(c[r]);
      hbf[r] = f2bf(hv[r]);
    }
    const int par = (int)(wt & 1u);
    unsigned long long* dst = &hx[((size_t)(par * 8 + bp)) * 1024 + w * 128 + lane * 2];
    const unsigned long long tg = ((unsigned long long)wt) << 32;
    __hip_atomic_store(&dst[0], tg | (unsigned long long)pk2(hv[0], hv[1]),
                       __ATOMIC_RELAXED, __HIP_MEMORY_SCOPE_AGENT);
    __hip_atomic_store(&dst[1], tg | (unsigned long long)pk2(hv[2], hv[3]),
                       __ATOMIC_RELAXED, __HIP_MEMORY_SCOPE_AGENT);
    asm volatile("" ::: "memory");
#pragma unroll
    for (int r = 0; r < 4; ++r) h_lds[par][ob + (hi * 4 + r) * 8] = hbf[r];
  };
  auto head = [&](int buf) {
    bf16x8 hh = *(const bf16x8*)&h_lds[buf][hb_g * 136 + hb_b * 8];
    float s = 0.f;
#pragma unroll
    for (int e = 0; e < 8; ++e) s += bf2f((unsigned short)hh[e]) * wv8[e];
    s += __shfl_xor(s, 1);  s += __shfl_xor(s, 2);  s += __shfl_xor(s, 4);
    s += __shfl_xor(s, 8);  s += __shfl_xor(s, 16);
    sig_acc += fsig(s + c0);
  };
  auto gx_issue = [&](int s, unsigned (&G)[8]) {
    const unsigned short* q = gp + (size_t)s * 65536;
    uint4 a = *(const uint4*)(q);
    uint4 b = *(const uint4*)(q + 8);
    G[0] = a.x; G[1] = a.y; G[2] = a.z; G[3] = a.w;
    G[4] = b.x; G[5] = b.y; G[6] = b.z; G[7] = b.w;
  };
  auto poll_write = [&](int t) {  // PL(t+1) + partner W2, 2-deep pipelined
    const unsigned wt = (unsigned)(t + 1);
    const int par = (int)(wt & 1u);
    unsigned long long* src = &hx[((size_t)(par * 8 + (bp ^ 1))) * 1024 + tid * 2];
    unsigned long long a0 = __hip_atomic_load(&src[0], __ATOMIC_RELAXED, __HIP_MEMORY_SCOPE_AGENT);
    unsigned long long a1 = __hip_atomic_load(&src[1], __ATOMIC_RELAXED, __HIP_MEMORY_SCOPE_AGENT);
    unsigned long long b0 = __hip_atomic_load(&src[0], __ATOMIC_RELAXED, __HIP_MEMORY_SCOPE_AGENT);
    unsigned long long b1 = __hip_atomic_load(&src[1], __ATOMIC_RELAXED, __HIP_MEMORY_SCOPE_AGENT);
    unsigned long long v0, v1;
    for (;;) {
      if ((unsigned)(a0 >> 32) == wt && (unsigned)(a1 >> 32) == wt) { v0 = a0; v1 = a1; break; }
      a0 = b0; a1 = b1;
      b0 = __hip_atomic_load(&src[0], __ATOMIC_RELAXED, __HIP_MEMORY_SCOPE_AGENT);
      b1 = __hip_atomic_load(&src[1], __ATOMIC_RELAXED, __HIP_MEMORY_SCOPE_AGENT);
    }
    h_lds[par][pb + (hip * 4 + 0) * 8] = (unsigned short)v0;
    h_lds[par][pb + (hip * 4 + 1) * 8] = (unsigned short)(v0 >> 16);
    h_lds[par][pb + (hip * 4 + 2) * 8] = (unsigned short)v1;
    h_lds[par][pb + (hip * 4 + 3) * 8] = (unsigned short)(v1 >> 16);
  };
  auto body = [&](int t, unsigned (&Gc)[8], unsigned (&Gf)[8]) {
    // entry: acc = gx(t)+bhh+own(h(t)); LDS[t&1] holds full h(t)
    mfma_par(t & 1);                 // complete gates(t)
    update_store(t);                 // h(t+1): store + own LDS
    if (t + 2 < TSTEPS) gx_issue(t + 2, Gf);
    __syncthreads();                 // B1: own writes visible
    if (t < TSTEPS - 1) {
      cinit(Gc);                     // gx(t+1)
      mfma_own((t + 1) & 1);         // own-half of step t+1 (shadow)
    }
    head(t & 1);                     // head of h(t) (shadow)
    poll_write(t);                   // partner h(t+1) -> LDS
    __syncthreads();                 // B2
  };

  // prologue: t=0 (h(0)=0 -> gates = gx(0)+bhh, no MFMA)
  cinit(gwE);
  update_store(0);
  gx_issue(2, gwE);
  __syncthreads();                   // B1
  cinit(gwO);
  mfma_own(1);
  poll_write(0);
  __syncthreads();                   // B2
  // main: t = 1..510 paired
  for (int t = 1; t + 1 < TSTEPS - 1; t += 2) {
    body(t, gwE, gwO);
    body(t + 1, gwO, gwE);
  }
  body(TSTEPS - 1, gwE, gwO);        // t=511 (no cinit/own/gx)
  head(0);                           // head of h(512) (buf 0)
  if (half == 0 && hb_g == 0) out[b0 + hb_b] = sig_acc * (1.f / 512.f);
#pragma unroll
  for (int r = 0; r < 4; ++r) {
    const int b = b0 + hi * 4 + r;
    out[64 + b * HDIM + j] = hv[r];
    out[64 + BATCH * HDIM + b * HDIM + j] = c[r];
  }
}

// ---------------- K3: w_eff[k] = sum_j Wf[j]*Wm[j][k]; weff[256] = bm.Wf+bf --
__global__ __launch_bounds__(256) void k_weff(const float* __restrict__ Wm,
                                              const float* __restrict__ bm,
                                              const float* __restrict__ Wf,
                                              const float* __restrict__ bfb,
                                              float* __restrict__ weff) {
  const int k = threadIdx.x;
  __shared__ float red[256];
  float acc = 0.f;
#pragma unroll 8
  for (int jj = 0; jj < 256; ++jj) acc += Wf[jj] * Wm[jj * 256 + k];
  weff[k] = acc;
  red[k] = bm[k] * Wf[k];
  __syncthreads();
  for (int s = 128; s > 0; s >>= 1) {
    if (k < s) red[k] += red[k + s];
    __syncthreads();
  }
  if (k == 0) weff[256] = red[0] + bfb[0];
}

extern "C" void kernel_launch(void* const* d_in, const int* in_sizes, int n_in,
                              void* d_out, int out_size, void* d_ws, size_t ws_size,
                              hipStream_t stream) {
  (void)in_sizes; (void)n_in; (void)out_size; (void)ws_size;
  const int* x = (const int*)d_in[0];
  const float* emb = (const float*)d_in[1];
  const float* Wih = (const float*)d_in[2];
  const float* Whh = (const float*)d_in[3];
  const float* bih = (const float*)d_in[4];
  const float* bhh = (const float*)d_in[5];
  const float* Wm  = (const float*)d_in[6];
  const float* bm  = (const float*)d_in[7];
  const float* Wf  = (const float*)d_in[8];
  const float* bf  = (const float*)d_in[9];
  float* out = (float*)d_out;
  char* ws = (char*)d_ws;
  const size_t gx_bytes = (size_t)TSTEPS * BATCH * G4H * 2;  // 67,108,864
  const size_t hx_bytes = (size_t)2 * 8 * 1024 * 8;          // 131,072
  unsigned short* gx3 = (unsigned short*)ws;
  unsigned long long* hx = (unsigned long long*)(ws + gx_bytes);
  float* weff = (float*)(ws + gx_bytes + hx_bytes);
  hipMemsetAsync(hx, 0, hx_bytes, stream);  // tags start at 0 every launch
  k_gx<<<dim3(512, 16), 256, 0, stream>>>(x, emb, Wih, bih, gx3);
  k_weff<<<1, 256, 0, stream>>>(Wm, bm, Wf, bf, weff);
  k_rec<<<8, 512, 0, stream>>>(gx3, Whh, bhh, weff, hx, out);
}